// Round 1
// baseline (437.814 us; speedup 1.0000x reference)
//
#include <hip/hip_runtime.h>
#include <hip/hip_bf16.h>

#define B_ 16
#define C_ 512
#define N_ 4096
#define EPSV 1e-6f

typedef __attribute__((ext_vector_type(8))) short bffrag;     // 8 bf16 (4 VGPR) MFMA A/B frag
typedef __attribute__((ext_vector_type(4))) float f32x4;      // MFMA C/D frag
typedef __attribute__((ext_vector_type(4))) unsigned short us4;
typedef __attribute__((ext_vector_type(8))) unsigned short us8;

__device__ __forceinline__ unsigned short f2bf(float f){
  unsigned u = __float_as_uint(f);
  u += 0x7fffu + ((u >> 16) & 1u);   // RNE; inputs are finite gaussians
  return (unsigned short)(u >> 16);
}

// ---------------------------------------------------------------------------
// K1: per-(b,n) reduction over channels: rnorm = 1/||V||, vsum = sum_c V,
//     rq = rnorm*(vsum*rnorm + eps)
// ---------------------------------------------------------------------------
__global__ __launch_bounds__(256) void k_reduce(const float* __restrict__ x,
    float* __restrict__ rnorm, float* __restrict__ vsum, float* __restrict__ rq){
  int idx = blockIdx.x * 256 + threadIdx.x;      // 0 .. B*N-1
  int b = idx >> 12;
  int n = idx & (N_ - 1);
  const float* p = x + (size_t)b * C_ * N_ + n;
  float s = 0.f, s2 = 0.f;
  #pragma unroll 8
  for (int c = 0; c < C_; ++c){
    float v = p[(size_t)c * N_];
    s += v; s2 += v * v;
  }
  float rn = 1.0f / sqrtf(s2);
  rnorm[idx] = rn;
  vsum[idx]  = s;
  rq[idx]    = rn * (s * rn + EPSV);
}

// ---------------------------------------------------------------------------
// K2: GEMM1  matrix[b,c,m] = sum_n V[c,n] * (V[m,n]*rnorm[n]),  split-K=2
//     partial buffers mpart[ks][b][c][m].  mt==0 blocks also compute
//     t[c] = sum_n V[c,n]*rq[n]  (partial over their K range) -> tpart.
// ---------------------------------------------------------------------------
__global__ __launch_bounds__(256) void k_gemm1(const float* __restrict__ x,
    const float* __restrict__ rnorm, const float* __restrict__ rq,
    float* __restrict__ mpart, float* __restrict__ tpart){
  const int b   = blockIdx.y;
  const int tile = blockIdx.x & 15;
  const int ks  = blockIdx.x >> 4;
  const int ct = tile >> 2, mt = tile & 3;
  const int c0 = ct * 128, m0 = mt * 128;

  __shared__ unsigned short As[128 * 40];   // [row c][k], k-padded 32->40
  __shared__ unsigned short Bs[128 * 40];   // [row m][k]
  __shared__ float tred[256];

  const int t = threadIdx.x;
  const int lrow = t >> 3;            // 0..31 staging row base
  const int lcg  = t & 7;             // float4 column group
  const int lane = t & 63, wave = t >> 6;
  const int wr = (wave & 1) * 64;     // wave c-offset
  const int wc = (wave >> 1) * 64;    // wave m-offset
  const int fr = lane & 15, quad = lane >> 4;

  const float* Ag  = x + (size_t)b * C_ * N_ + (size_t)c0 * N_;
  const float* Bg  = x + (size_t)b * C_ * N_ + (size_t)m0 * N_;
  const float* rn  = rnorm + (size_t)b * N_;
  const float* rqp = rq    + (size_t)b * N_;

  f32x4 acc[4][4];
  #pragma unroll
  for (int i = 0; i < 4; ++i)
    #pragma unroll
    for (int j = 0; j < 4; ++j) acc[i][j] = (f32x4){0.f, 0.f, 0.f, 0.f};
  float tacc[4] = {0.f, 0.f, 0.f, 0.f};

  for (int kc = 0; kc < 64; ++kc){
    const int k0 = ks * 2048 + kc * 32;
    float4 av[4], bv[4];
    float4 rv = *(const float4*)&rn[k0 + lcg * 4];
    #pragma unroll
    for (int u = 0; u < 4; ++u){
      int row = lrow + u * 32;
      av[u] = *(const float4*)&Ag[(size_t)row * N_ + k0 + lcg * 4];
      bv[u] = *(const float4*)&Bg[(size_t)row * N_ + k0 + lcg * 4];
    }
    if (mt == 0){   // fused tailor-denominator dot (A elements loaded anyway)
      float4 qv = *(const float4*)&rqp[k0 + lcg * 4];
      #pragma unroll
      for (int u = 0; u < 4; ++u)
        tacc[u] += av[u].x*qv.x + av[u].y*qv.y + av[u].z*qv.z + av[u].w*qv.w;
    }
    __syncthreads();          // previous iter's frag reads done
    #pragma unroll
    for (int u = 0; u < 4; ++u){
      int row = lrow + u * 32;
      us4 aw; aw.x = f2bf(av[u].x); aw.y = f2bf(av[u].y);
              aw.z = f2bf(av[u].z); aw.w = f2bf(av[u].w);
      *(us4*)&As[row * 40 + lcg * 4] = aw;
      us4 bw; bw.x = f2bf(bv[u].x * rv.x); bw.y = f2bf(bv[u].y * rv.y);
              bw.z = f2bf(bv[u].z * rv.z); bw.w = f2bf(bv[u].w * rv.w);
      *(us4*)&Bs[row * 40 + lcg * 4] = bw;
    }
    __syncthreads();
    bffrag af[4], bf[4];
    #pragma unroll
    for (int i = 0; i < 4; ++i)
      af[i] = *(const bffrag*)&As[(wr + i * 16 + fr) * 40 + quad * 8];
    #pragma unroll
    for (int j = 0; j < 4; ++j)
      bf[j] = *(const bffrag*)&Bs[(wc + j * 16 + fr) * 40 + quad * 8];
    #pragma unroll
    for (int i = 0; i < 4; ++i)
      #pragma unroll
      for (int j = 0; j < 4; ++j)
        acc[i][j] = __builtin_amdgcn_mfma_f32_16x16x32_bf16(af[i], bf[j], acc[i][j], 0, 0, 0);
  }

  float* op = mpart + ((size_t)(ks * 16 + b)) * (C_ * C_);
  #pragma unroll
  for (int i = 0; i < 4; ++i)
    #pragma unroll
    for (int r = 0; r < 4; ++r){
      int c = c0 + wr + i * 16 + quad * 4 + r;
      #pragma unroll
      for (int j = 0; j < 4; ++j){
        int m = m0 + wc + j * 16 + fr;
        op[(size_t)c * C_ + m] = acc[i][j][r];
      }
    }

  if (mt == 0){
    float* tp = tpart + ((size_t)(ks * 16 + b)) * C_ + c0;
    #pragma unroll
    for (int u = 0; u < 4; ++u){
      __syncthreads();
      tred[t] = tacc[u];
      __syncthreads();
      if (lcg == 0){
        float s = 0.f;
        #pragma unroll
        for (int z = 0; z < 8; ++z) s += tred[lrow * 8 + z];
        tp[lrow + u * 32] = s;
      }
    }
  }
}

// ---------------------------------------------------------------------------
// K2b: matrix = mpart[0] + mpart[1], converted to bf16 (A operand of GEMM2)
// ---------------------------------------------------------------------------
__global__ __launch_bounds__(256) void k_sumcvt(const float* __restrict__ mpart,
                                                unsigned short* __restrict__ Ab){
  int idx = blockIdx.x * 256 + threadIdx.x;     // * 4 elements
  f32x4 a = *(const f32x4*)&mpart[idx * 4];
  f32x4 c = *(const f32x4*)&mpart[idx * 4 + B_ * C_ * C_];
  us4 o;
  o.x = f2bf(a.x + c.x); o.y = f2bf(a.y + c.y);
  o.z = f2bf(a.z + c.z); o.w = f2bf(a.w + c.w);
  *(us4*)&Ab[idx * 4] = o;
}

// ---------------------------------------------------------------------------
// K3: GEMM2 + epilogue
//   out[c,n] = x[c,n] + gamma*((vsum[n] + sum_m matrix[c,m]*Qn[m,n])*tailor[c])
//   A = matrix bf16 (k=m contiguous).  B = Qn[m,n]: transposed into LDS [n][k=m].
// ---------------------------------------------------------------------------
__global__ __launch_bounds__(256) void k_gemm2(const float* __restrict__ x,
    const unsigned short* __restrict__ Ab, const float* __restrict__ rnorm,
    const float* __restrict__ vsum, const float* __restrict__ tpart,
    const float* __restrict__ gamma, float* __restrict__ out){
  const int b  = blockIdx.y;
  const int ct = blockIdx.x >> 5;
  const int nt = blockIdx.x & 31;
  const int c0 = ct * 128, n0 = nt * 128;

  __shared__ unsigned short As[128 * 40];   // [row c][k=m]
  __shared__ unsigned short Bs[128 * 40];   // [row n][k=m]
  __shared__ float tl[128];

  const int t = threadIdx.x;
  if (t < 128){
    float tv = tpart[(size_t)b * C_ + c0 + t] + tpart[(size_t)(16 + b) * C_ + c0 + t];
    tl[t] = 1.0f / ((float)N_ + tv);
  }
  const int lane = t & 63, wave = t >> 6;
  const int wr = (wave & 1) * 64;    // c
  const int wc = (wave >> 1) * 64;   // n
  const int fr = lane & 15, quad = lane >> 4;

  const int arow = t >> 2;           // A staging: 0..63 (+64)
  const int acg  = t & 3;
  const int nloc = t & 127;          // B staging (transpose)
  const int mh   = t >> 7;           // 0/1: which 16 of the 32 k's

  const float rnn = rnorm[(size_t)b * N_ + n0 + nloc];
  const float* xb = x + (size_t)b * C_ * N_;
  const unsigned short* Abb = Ab + (size_t)b * C_ * C_;

  f32x4 acc[4][4];
  #pragma unroll
  for (int i = 0; i < 4; ++i)
    #pragma unroll
    for (int j = 0; j < 4; ++j) acc[i][j] = (f32x4){0.f, 0.f, 0.f, 0.f};

  for (int kc = 0; kc < 16; ++kc){
    const int m0 = kc * 32;
    us8 av[2];
    #pragma unroll
    for (int u = 0; u < 2; ++u){
      int row = arow + u * 64;
      av[u] = *(const us8*)&Abb[(size_t)(c0 + row) * C_ + m0 + acg * 8];
    }
    float bval[16];
    #pragma unroll
    for (int j = 0; j < 16; ++j)    // strided rows, coalesced across lanes (n)
      bval[j] = xb[(size_t)(m0 + mh * 16 + j) * N_ + n0 + nloc] * rnn;
    __syncthreads();
    #pragma unroll
    for (int u = 0; u < 2; ++u){
      int row = arow + u * 64;
      *(us8*)&As[row * 40 + acg * 8] = av[u];
    }
    #pragma unroll
    for (int g = 0; g < 2; ++g){
      us8 w;
      #pragma unroll
      for (int j = 0; j < 8; ++j) w[j] = f2bf(bval[g * 8 + j]);
      *(us8*)&Bs[nloc * 40 + mh * 16 + g * 8] = w;   // [n][k] transposed store
    }
    __syncthreads();
    bffrag af[4], bf[4];
    #pragma unroll
    for (int i = 0; i < 4; ++i)
      af[i] = *(const bffrag*)&As[(wr + i * 16 + fr) * 40 + quad * 8];
    #pragma unroll
    for (int j = 0; j < 4; ++j)
      bf[j] = *(const bffrag*)&Bs[(wc + j * 16 + fr) * 40 + quad * 8];
    #pragma unroll
    for (int i = 0; i < 4; ++i)
      #pragma unroll
      for (int j = 0; j < 4; ++j)
        acc[i][j] = __builtin_amdgcn_mfma_f32_16x16x32_bf16(af[i], bf[j], acc[i][j], 0, 0, 0);
  }

  const float g = gamma[0];
  const float* vs = vsum + (size_t)b * N_;
  float* ob = out + (size_t)b * C_ * N_;
  #pragma unroll
  for (int i = 0; i < 4; ++i)
    #pragma unroll
    for (int r = 0; r < 4; ++r){
      int c = c0 + wr + i * 16 + quad * 4 + r;
      float tll = tl[wr + i * 16 + quad * 4 + r];
      #pragma unroll
      for (int j = 0; j < 4; ++j){
        int n = n0 + wc + j * 16 + fr;
        float xv = xb[(size_t)c * N_ + n];
        ob[(size_t)c * N_ + n] = xv + g * ((vs[n] + acc[i][j][r]) * tll);
      }
    }
}

// ---------------------------------------------------------------------------
extern "C" void kernel_launch(void* const* d_in, const int* in_sizes, int n_in,
                              void* d_out, int out_size, void* d_ws, size_t ws_size,
                              hipStream_t stream){
  const float* x     = (const float*)d_in[0];
  const float* gamma = (const float*)d_in[1];
  float* out = (float*)d_out;
  char* ws = (char*)d_ws;

  // ws layout (bytes):
  float* mpart = (float*)(ws);                         // 2*16*512*512*4 = 33,554,432
  float* rnorm = (float*)(ws + 33554432);              // 262,144
  float* vsum  = (float*)(ws + 33816576);              // 262,144
  float* rq    = (float*)(ws + 34078720);              // 262,144
  float* tpart = (float*)(ws + 34340864);              // 2*16*512*4 = 65,536
  unsigned short* Ab = (unsigned short*)(ws + 34406400); // 16*512*512*2 = 8,388,608
  // total 42,795,008 bytes

  k_reduce<<<dim3((B_ * N_) / 256), 256, 0, stream>>>(x, rnorm, vsum, rq);
  k_gemm1<<<dim3(32, B_), 256, 0, stream>>>(x, rnorm, rq, mpart, tpart);
  k_sumcvt<<<dim3((B_ * C_ * C_) / 4 / 256), 256, 0, stream>>>(mpart, Ab);
  k_gemm2<<<dim3(128, B_), 256, 0, stream>>>(x, Ab, rnorm, vsum, tpart, gamma, out);
}